// Round 2
// baseline (10305.479 us; speedup 1.0000x reference)
//
#include <hip/hip_runtime.h>

#define BATCH 64
#define NTOK 198
#define CDIM 768
#define NHEAD 12
#define HDIM 64
#define NLAYER 12
#define ATT_SCALE 0.125f
#define LDSK 40      // 32 + 8 pad (bf16 elems)
#define SLD 208      // padded score row stride (floats, 16B aligned)

typedef __attribute__((ext_vector_type(8))) __bf16 bf16x8;
typedef __attribute__((ext_vector_type(4))) float f32x4;

__device__ __forceinline__ unsigned f2bf_bits(float a) {
    unsigned u = __builtin_bit_cast(unsigned, a);
    return (u + 0x7FFFu + ((u >> 16) & 1u)) >> 16;   // RNE; inputs are finite
}
__device__ __forceinline__ unsigned pkbf(float a, float b) {
    return f2bf_bits(a) | (f2bf_bits(b) << 16);
}
__device__ __forceinline__ short f2bf(float a) {
    return (short)f2bf_bits(a);
}

#define EPI_NONE 0
#define EPI_BIAS 1
#define EPI_GELU 2
#define EPI_RES  3

// C[M,N] = A[M,K] * Bt[N,K]^T ; all tile dims multiples of 128, K multiple of 32.
template<int EPI>
__global__ __launch_bounds__(256)
void gemm_bt(const float* __restrict__ A, const float* __restrict__ Bt,
             const float* __restrict__ bias, float* __restrict__ C,
             int lda, int ldb, int ldc, int K)
{
    __shared__ short sA[128 * LDSK];
    __shared__ short sB[128 * LDSK];
    const int tid = threadIdx.x;
    const int lane = tid & 63, wave = tid >> 6;
    const int wm = wave >> 1, wn = wave & 1;
    const int quad = lane >> 4, r = lane & 15;
    const int m0 = blockIdx.y * 128, n0 = blockIdx.x * 128;

    const int srow = tid >> 1;
    const int shalf = (tid & 1) << 4;
    const float* aptr = A + (size_t)(m0 + srow) * lda + shalf;
    const float* bptr = Bt + (size_t)(n0 + srow) * ldb + shalf;
    short* sAw = sA + srow * LDSK + shalf;
    short* sBw = sB + srow * LDSK + shalf;

    const f32x4 vzero = {0.f, 0.f, 0.f, 0.f};
    f32x4 acc[4][4];
#pragma unroll
    for (int i = 0; i < 4; ++i)
#pragma unroll
        for (int j = 0; j < 4; ++j) acc[i][j] = vzero;

    for (int k0 = 0; k0 < K; k0 += 32) {
        float4 a0 = *(const float4*)(aptr + k0);
        float4 a1 = *(const float4*)(aptr + k0 + 4);
        float4 a2 = *(const float4*)(aptr + k0 + 8);
        float4 a3 = *(const float4*)(aptr + k0 + 12);
        float4 b0 = *(const float4*)(bptr + k0);
        float4 b1 = *(const float4*)(bptr + k0 + 4);
        float4 b2 = *(const float4*)(bptr + k0 + 8);
        float4 b3 = *(const float4*)(bptr + k0 + 12);
        __syncthreads();
        *(uint4*)(sAw)     = make_uint4(pkbf(a0.x,a0.y), pkbf(a0.z,a0.w), pkbf(a1.x,a1.y), pkbf(a1.z,a1.w));
        *(uint4*)(sAw + 8) = make_uint4(pkbf(a2.x,a2.y), pkbf(a2.z,a2.w), pkbf(a3.x,a3.y), pkbf(a3.z,a3.w));
        *(uint4*)(sBw)     = make_uint4(pkbf(b0.x,b0.y), pkbf(b0.z,b0.w), pkbf(b1.x,b1.y), pkbf(b1.z,b1.w));
        *(uint4*)(sBw + 8) = make_uint4(pkbf(b2.x,b2.y), pkbf(b2.z,b2.w), pkbf(b3.x,b3.y), pkbf(b3.z,b3.w));
        __syncthreads();
        bf16x8 af[4], bfv[4];
#pragma unroll
        for (int i = 0; i < 4; ++i)
            af[i] = *(const bf16x8*)(sA + (wm*64 + i*16 + r) * LDSK + quad*8);
#pragma unroll
        for (int j = 0; j < 4; ++j)
            bfv[j] = *(const bf16x8*)(sB + (wn*64 + j*16 + r) * LDSK + quad*8);
#pragma unroll
        for (int i = 0; i < 4; ++i)
#pragma unroll
            for (int j = 0; j < 4; ++j)
                acc[i][j] = __builtin_amdgcn_mfma_f32_16x16x32_bf16(af[i], bfv[j], acc[i][j], 0, 0, 0);
    }

#pragma unroll
    for (int i = 0; i < 4; ++i) {
        const int row0 = m0 + wm*64 + i*16 + quad*4;
#pragma unroll
        for (int j = 0; j < 4; ++j) {
            const int col = n0 + wn*64 + j*16 + r;
            float bv = 0.f;
            if (EPI != EPI_NONE) bv = bias[col];
#pragma unroll
            for (int t = 0; t < 4; ++t) {
                size_t idx = (size_t)(row0 + t) * ldc + col;
                float v = acc[i][j][t];
                if (EPI == EPI_NONE) C[idx] = v;
                else if (EPI == EPI_BIAS) C[idx] = v + bv;
                else if (EPI == EPI_GELU) {
                    float u = v + bv;
                    C[idx] = 0.5f * u * (1.f + erff(u * 0.70710678f));
                } else {
                    C[idx] = C[idx] + v + bv;
                }
            }
        }
    }
}

__global__ __launch_bounds__(256)
void im2col_kernel(const float* __restrict__ x, float* __restrict__ out)
{
    int idx = blockIdx.x * 256 + threadIdx.x;       // 12544*768 total, exact
    int kk = idx % 768;
    int m = idx / 768;
    int c = kk >> 8, rr = kk & 255, i = rr >> 4, j = rr & 15;
    int b = m / 196, p = m % 196, ph = p / 14, pw = p % 14;
    out[idx] = x[(((size_t)(b*3 + c) * 224) + ph*16 + i) * 224 + pw*16 + j];
}

__global__ __launch_bounds__(256)
void build_t_kernel(const float* __restrict__ pbuf, const float* __restrict__ cls_tok,
                    const float* __restrict__ loc_tok, const float* __restrict__ pos_emb,
                    const float* __restrict__ loc_emb, float* __restrict__ t)
{
    int idx = blockIdx.x * 256 + threadIdx.x;       // 64*198*768, exact
    int c = idx % CDIM;
    int bn = idx / CDIM;
    int n = bn % NTOK, b = bn / NTOK;
    float v;
    if (n == 0)          v = cls_tok[c] + pos_emb[c];
    else if (n == NTOK-1) v = loc_tok[c] + loc_emb[c];
    else                 v = pbuf[((size_t)(b*196 + n - 1)) * CDIM + c] + pos_emb[(size_t)n * CDIM + c];
    t[idx] = v;
}

__global__ __launch_bounds__(256)
void ln_kernel(const float* __restrict__ x, const float* __restrict__ w,
               const float* __restrict__ bb, float* __restrict__ y)
{
    int row = blockIdx.x;
    const float* xr = x + (size_t)row * CDIM;
    int tid = threadIdx.x;
    float v0 = xr[tid], v1 = xr[tid + 256], v2 = xr[tid + 512];
    float s = v0 + v1 + v2;
    float q = v0*v0 + v1*v1 + v2*v2;
#pragma unroll
    for (int off = 32; off; off >>= 1) {
        s += __shfl_down(s, off, 64);
        q += __shfl_down(q, off, 64);
    }
    __shared__ float rs[4], rq[4];
    int lane = tid & 63, wv = tid >> 6;
    if (lane == 0) { rs[wv] = s; rq[wv] = q; }
    __syncthreads();
    float S = rs[0] + rs[1] + rs[2] + rs[3];
    float Q = rq[0] + rq[1] + rq[2] + rq[3];
    float mean = S * (1.f / 768.f);
    float var = Q * (1.f / 768.f) - mean * mean;
    float rstd = rsqrtf(var + 1e-5f);
    float* yr = y + (size_t)row * CDIM;
    yr[tid]       = (v0 - mean) * rstd * w[tid]       + bb[tid];
    yr[tid + 256] = (v1 - mean) * rstd * w[tid + 256] + bb[tid + 256];
    yr[tid + 512] = (v2 - mean) * rstd * w[tid + 512] + bb[tid + 512];
}

// S[bh, q, k] = scale * Q.K^T   (tiles 64x64, K=64)
__global__ __launch_bounds__(256)
void attn_score(const float* __restrict__ qkv, float* __restrict__ S)
{
    const int bh = blockIdx.z, b = bh / NHEAD, h = bh % NHEAD;
    const int m0 = blockIdx.y * 64, n0 = blockIdx.x * 64;
    __shared__ short sQ[64 * 72];
    __shared__ short sK[64 * 72];
    const int tid = threadIdx.x;
    const int lane = tid & 63, wave = tid >> 6;
    const int wm = wave >> 1, wn = wave & 1;
    const int quad = lane >> 4, r = lane & 15;

    const float* base = qkv + (size_t)b * NTOK * 2304 + h * 64;
    {
        const int srow = tid >> 2, seg = (tid & 3) << 4;
        int gq = m0 + srow, gk = n0 + srow;
        float4 z = make_float4(0.f, 0.f, 0.f, 0.f);
        float4 q0=z,q1=z,q2=z,q3=z,k0=z,k1=z,k2=z,k3=z;
        if (gq < NTOK) {
            const float* p = base + (size_t)gq * 2304 + seg;
            q0 = *(const float4*)(p);     q1 = *(const float4*)(p + 4);
            q2 = *(const float4*)(p + 8); q3 = *(const float4*)(p + 12);
        }
        if (gk < NTOK) {
            const float* p = base + (size_t)gk * 2304 + 768 + seg;
            k0 = *(const float4*)(p);     k1 = *(const float4*)(p + 4);
            k2 = *(const float4*)(p + 8); k3 = *(const float4*)(p + 12);
        }
        short* wq = sQ + srow * 72 + seg;
        *(uint4*)(wq)     = make_uint4(pkbf(q0.x,q0.y), pkbf(q0.z,q0.w), pkbf(q1.x,q1.y), pkbf(q1.z,q1.w));
        *(uint4*)(wq + 8) = make_uint4(pkbf(q2.x,q2.y), pkbf(q2.z,q2.w), pkbf(q3.x,q3.y), pkbf(q3.z,q3.w));
        short* wk = sK + srow * 72 + seg;
        *(uint4*)(wk)     = make_uint4(pkbf(k0.x,k0.y), pkbf(k0.z,k0.w), pkbf(k1.x,k1.y), pkbf(k1.z,k1.w));
        *(uint4*)(wk + 8) = make_uint4(pkbf(k2.x,k2.y), pkbf(k2.z,k2.w), pkbf(k3.x,k3.y), pkbf(k3.z,k3.w));
    }
    __syncthreads();

    const f32x4 vzero = {0.f, 0.f, 0.f, 0.f};
    f32x4 acc[2][2] = {{vzero, vzero}, {vzero, vzero}};
#pragma unroll
    for (int ks = 0; ks < 2; ++ks) {
        bf16x8 aq0 = *(const bf16x8*)(sQ + (wm*32 + r)      * 72 + ks*32 + quad*8);
        bf16x8 aq1 = *(const bf16x8*)(sQ + (wm*32 + 16 + r) * 72 + ks*32 + quad*8);
        bf16x8 bk0 = *(const bf16x8*)(sK + (wn*32 + r)      * 72 + ks*32 + quad*8);
        bf16x8 bk1 = *(const bf16x8*)(sK + (wn*32 + 16 + r) * 72 + ks*32 + quad*8);
        acc[0][0] = __builtin_amdgcn_mfma_f32_16x16x32_bf16(aq0, bk0, acc[0][0], 0, 0, 0);
        acc[0][1] = __builtin_amdgcn_mfma_f32_16x16x32_bf16(aq0, bk1, acc[0][1], 0, 0, 0);
        acc[1][0] = __builtin_amdgcn_mfma_f32_16x16x32_bf16(aq1, bk0, acc[1][0], 0, 0, 0);
        acc[1][1] = __builtin_amdgcn_mfma_f32_16x16x32_bf16(aq1, bk1, acc[1][1], 0, 0, 0);
    }
#pragma unroll
    for (int i = 0; i < 2; ++i)
#pragma unroll
        for (int j = 0; j < 2; ++j)
#pragma unroll
            for (int t = 0; t < 4; ++t) {
                int qr = m0 + wm*32 + i*16 + quad*4 + t;
                int kc = n0 + wn*32 + j*16 + r;
                if (qr < NTOK && kc < NTOK)
                    S[((size_t)bh * NTOK + qr) * SLD + kc] = acc[i][j][t] * ATT_SCALE;
            }
}

__global__ __launch_bounds__(256)
void mask_kernel(const float* __restrict__ S, float* __restrict__ mk)
{
    int b = blockIdx.x, kc = threadIdx.x;
    if (kc >= NTOK) return;
    float s = 0.f;
#pragma unroll
    for (int h = 0; h < NHEAD; ++h)
        s += S[((size_t)(b * NHEAD + h) * NTOK + (NTOK - 1)) * SLD + kc];
    s *= (1.f / NHEAD);
    mk[b * NTOK + kc] = 1.f / (1.f + __expf(-s));
}

__global__ __launch_bounds__(256)
void softmax_kernel(float* __restrict__ S, const float* __restrict__ mk, int use_mask)
{
    int bh = blockIdx.y, b = bh / NHEAD;
    int qr = blockIdx.x * 4 + (threadIdx.x >> 6);
    int lane = threadIdx.x & 63;
    if (qr >= NTOK) return;
    float* row = S + ((size_t)bh * NTOK + qr) * SLD;
    float v0 = row[lane];
    float v1 = row[lane + 64];
    float v2 = row[lane + 128];
    float v3 = (lane + 192 < NTOK) ? row[lane + 192] : -1e30f;
    float mx = fmaxf(fmaxf(v0, v1), fmaxf(v2, v3));
#pragma unroll
    for (int off = 32; off; off >>= 1) mx = fmaxf(mx, __shfl_xor(mx, off, 64));
    v0 = __expf(v0 - mx); v1 = __expf(v1 - mx); v2 = __expf(v2 - mx);
    v3 = (lane + 192 < NTOK) ? __expf(v3 - mx) : 0.f;
    float sm = v0 + v1 + v2 + v3;
#pragma unroll
    for (int off = 32; off; off >>= 1) sm += __shfl_xor(sm, off, 64);
    float inv = 1.f / sm;
    v0 *= inv; v1 *= inv; v2 *= inv; v3 *= inv;
    if (use_mask) {
        v0 *= mk[b * NTOK + lane];
        v1 *= mk[b * NTOK + lane + 64];
        v2 *= mk[b * NTOK + lane + 128];
        if (lane + 192 < NTOK) v3 *= mk[b * NTOK + lane + 192];
    }
    row[lane] = v0; row[lane + 64] = v1; row[lane + 128] = v2;
    if (lane + 192 < NTOK) row[lane + 192] = v3;
}

// O[b,q,h*64+hd] = P.V  (tiles 64 rows x 64 hd, K over 198)
__global__ __launch_bounds__(256)
void attn_pv(const float* __restrict__ S, const float* __restrict__ qkv, float* __restrict__ o)
{
    const int bh = blockIdx.y, b = bh / NHEAD, h = bh % NHEAD;
    const int m0 = blockIdx.x * 64;
    __shared__ short sP[64 * LDSK];
    __shared__ short sVt[64 * LDSK];
    const int tid = threadIdx.x;
    const int lane = tid & 63, wave = tid >> 6;
    const int wm = wave >> 1, wn = wave & 1;
    const int quad = lane >> 4, r = lane & 15;
    const float* Pb = S + (size_t)bh * NTOK * SLD;
    const float* vb = qkv + (size_t)b * NTOK * 2304 + 1536 + h * 64;

    const f32x4 vzero = {0.f, 0.f, 0.f, 0.f};
    f32x4 acc[2][2] = {{vzero, vzero}, {vzero, vzero}};

    const int prow = tid >> 2, pseg = (tid & 3) << 3;
    const int vk = tid & 31, vh = (tid >> 5) << 3;

    for (int k0 = 0; k0 < NTOK; k0 += 32) {
        __syncthreads();
        {
            int gq = m0 + prow;
            short* w = sP + prow * LDSK + pseg;
            if (gq < NTOK) {
#pragma unroll
                for (int e = 0; e < 8; ++e) {
                    int k = k0 + pseg + e;
                    w[e] = (k < NTOK) ? f2bf(Pb[(size_t)gq * SLD + k]) : (short)0;
                }
            } else {
#pragma unroll
                for (int e = 0; e < 8; ++e) w[e] = 0;
            }
        }
        {
            int gk = k0 + vk;
            if (gk < NTOK) {
                const float* p = vb + (size_t)gk * 2304 + vh;
#pragma unroll
                for (int e = 0; e < 8; ++e) sVt[(vh + e) * LDSK + vk] = f2bf(p[e]);
            } else {
#pragma unroll
                for (int e = 0; e < 8; ++e) sVt[(vh + e) * LDSK + vk] = 0;
            }
        }
        __syncthreads();
        bf16x8 ap0 = *(const bf16x8*)(sP + (wm*32 + r)       * LDSK + quad*8);
        bf16x8 ap1 = *(const bf16x8*)(sP + (wm*32 + 16 + r)  * LDSK + quad*8);
        bf16x8 bv0 = *(const bf16x8*)(sVt + (wn*32 + r)      * LDSK + quad*8);
        bf16x8 bv1 = *(const bf16x8*)(sVt + (wn*32 + 16 + r) * LDSK + quad*8);
        acc[0][0] = __builtin_amdgcn_mfma_f32_16x16x32_bf16(ap0, bv0, acc[0][0], 0, 0, 0);
        acc[0][1] = __builtin_amdgcn_mfma_f32_16x16x32_bf16(ap0, bv1, acc[0][1], 0, 0, 0);
        acc[1][0] = __builtin_amdgcn_mfma_f32_16x16x32_bf16(ap1, bv0, acc[1][0], 0, 0, 0);
        acc[1][1] = __builtin_amdgcn_mfma_f32_16x16x32_bf16(ap1, bv1, acc[1][1], 0, 0, 0);
    }
#pragma unroll
    for (int i = 0; i < 2; ++i) {
        int qr0 = m0 + wm*32 + i*16 + quad*4;
#pragma unroll
        for (int j = 0; j < 2; ++j) {
            int hd = wn*32 + j*16 + r;
#pragma unroll
            for (int t = 0; t < 4; ++t) {
                int qr = qr0 + t;
                if (qr < NTOK)
                    o[((size_t)b * NTOK + qr) * CDIM + h * HDIM + hd] = acc[i][j][t];
            }
        }
    }
}

// 9 shifted-window sums of the final-LN patch tokens: Ssum[b, c*9 + di*3 + dj]
__global__ __launch_bounds__(256)
void ssum_kernel(const float* __restrict__ tn, float* __restrict__ ss)
{
    int b = blockIdx.x;
    for (int c = threadIdx.x; c < CDIM; c += 256) {
        float rs0[14], rs1[14], rs2[14];
#pragma unroll
        for (int y = 0; y < 14; ++y) {
            float sum = 0.f, first = 0.f, last = 0.f;
#pragma unroll
            for (int xx = 0; xx < 14; ++xx) {
                float v = tn[((size_t)(b * NTOK + 1 + y * 14 + xx)) * CDIM + c];
                sum += v;
                if (xx == 0) first = v;
                if (xx == 13) last = v;
            }
            rs1[y] = sum; rs0[y] = sum - last; rs2[y] = sum - first;
        }
        float a0 = 0.f, a1 = 0.f, a2 = 0.f;
#pragma unroll
        for (int y = 0; y < 14; ++y) { a0 += rs0[y]; a1 += rs1[y]; a2 += rs2[y]; }
        float* outp = ss + (size_t)b * 6912 + c * 9;
        outp[0] = a0 - rs0[13]; outp[1] = a1 - rs1[13]; outp[2] = a2 - rs2[13];
        outp[3] = a0;           outp[4] = a1;           outp[5] = a2;
        outp[6] = a0 - rs0[0];  outp[7] = a1 - rs1[0];  outp[8] = a2 - rs2[0];
    }
}

__global__ __launch_bounds__(256)
void logits_kernel(const float* __restrict__ ssum, const float* __restrict__ hw,
                   const float* __restrict__ hb, float* __restrict__ out)
{
    int cls = blockIdx.x;
    int lane = threadIdx.x & 63, wave = threadIdx.x >> 6;
    const float* wr = hw + (size_t)cls * 6912;
    for (int b = wave; b < BATCH; b += 4) {
        const float* sr = ssum + (size_t)b * 6912;
        float s = 0.f;
        for (int k = lane; k < 6912; k += 64) s += sr[k] * wr[k];
#pragma unroll
        for (int off = 32; off; off >>= 1) s += __shfl_down(s, off, 64);
        if (lane == 0) out[b * 200 + cls] = hb[cls] + s * (1.f / 196.f);
    }
}

__global__ __launch_bounds__(256)
void mask_out_kernel(const float* __restrict__ masks, const float* __restrict__ gk,
                     float* __restrict__ out)
{
    int b = blockIdx.x, tid = threadIdx.x;
    __shared__ float sm[196];
    float ma = 0.f;
    if (tid < 196) {
        float m0 = masks[((size_t)(0 * BATCH + b)) * NTOK + tid + 1];
        float m1 = masks[((size_t)(1 * BATCH + b)) * NTOK + tid + 1];
        float m2 = masks[((size_t)(2 * BATCH + b)) * NTOK + tid + 1];
        ma = (m0 + m1 + m2) * (1.f / 3.f);
        sm[tid] = ma;
    }
    __syncthreads();
    float mavg = 0.f;
    if (tid < 196) {
        int i = tid / 14, j = tid % 14;
#pragma unroll
        for (int di = 0; di < 3; ++di)
#pragma unroll
            for (int dj = 0; dj < 3; ++dj) {
                int y = i + di - 1, xx = j + dj - 1;
                if (y >= 0 && y < 14 && xx >= 0 && xx < 14)
                    mavg += gk[di * 3 + dj] * sm[y * 14 + xx];
            }
    }
    float rg = (1.f - mavg) * mavg;
    if (tid >= 196) { ma = 0.f; rg = 0.f; }
    float s1 = ma, s2 = rg;
#pragma unroll
    for (int off = 32; off; off >>= 1) { s1 += __shfl_down(s1, off, 64); s2 += __shfl_down(s2, off, 64); }
    __shared__ float r1[4], r2[4];
    if ((tid & 63) == 0) { r1[tid >> 6] = s1; r2[tid >> 6] = s2; }
    __syncthreads();
    if (tid == 0) {
        out[12800 + b] = (r1[0] + r1[1] + r1[2] + r1[3]) * (1.f / 196.f);
        out[12864 + b] = (r2[0] + r2[1] + r2[2] + r2[3]) * (1.f / 196.f);
    }
}

extern "C" void kernel_launch(void* const* d_in, const int* in_sizes, int n_in,
                              void* d_out, int out_size, void* d_ws, size_t ws_size,
                              hipStream_t stream)
{
    const float* x       = (const float*)d_in[0];
    const float* patch_w = (const float*)d_in[1];
    const float* patch_b = (const float*)d_in[2];
    const float* cls_tok = (const float*)d_in[3];
    const float* loc_tok = (const float*)d_in[4];
    const float* pos_emb = (const float*)d_in[5];
    const float* loc_emb = (const float*)d_in[6];
    const float* ln1_w   = (const float*)d_in[7];
    const float* ln1_b   = (const float*)d_in[8];
    const float* qkv_w   = (const float*)d_in[9];
    const float* proj_w  = (const float*)d_in[10];
    const float* proj_b  = (const float*)d_in[11];
    const float* ln2_w   = (const float*)d_in[12];
    const float* ln2_b   = (const float*)d_in[13];
    const float* fc1_w   = (const float*)d_in[14];
    const float* fc1_b   = (const float*)d_in[15];
    const float* fc2_w   = (const float*)d_in[16];
    const float* fc2_b   = (const float*)d_in[17];
    const float* norm_w  = (const float*)d_in[18];
    const float* norm_b  = (const float*)d_in[19];
    const float* head_w  = (const float*)d_in[20];
    const float* head_b  = (const float*)d_in[21];
    const float* gk      = (const float*)d_in[22];
    float* out = (float*)d_out;
    float* ws = (float*)d_ws;

    // workspace layout (floats)
    float* t_buf  = ws;                       // 64*198*768 = 9,732,096
    float* a_buf  = ws + 9732096;             // 9,732,096
    float* qkvbuf = ws + 2 * 9732096;         // 29,196,288 (also pbuf at start)
    float* h_buf  = ws + 19464192 + 29196288; // 38,928,384 (also S / im2col)
    float* ssum   = ws + 48660480 + 38928384; // 442,368
    float* masks  = ssum + 442368;            // 3*64*198 = 38,016
    float* S      = h_buf;
    float* im2c   = h_buf;
    float* p_buf  = qkvbuf;

    im2col_kernel<<<37632, 256, 0, stream>>>(x, im2c);
    gemm_bt<EPI_BIAS><<<dim3(6, 98), 256, 0, stream>>>(im2c, patch_w, patch_b, p_buf, 768, 768, 768, 768);
    build_t_kernel<<<38016, 256, 0, stream>>>(p_buf, cls_tok, loc_tok, pos_emb, loc_emb, t_buf);

    for (int d = 0; d < NLAYER; ++d) {
        ln_kernel<<<12672, 256, 0, stream>>>(t_buf, ln1_w + d * CDIM, ln1_b + d * CDIM, a_buf);
        gemm_bt<EPI_NONE><<<dim3(18, 99), 256, 0, stream>>>(a_buf, qkv_w + (size_t)d * 3 * CDIM * CDIM,
                                                            nullptr, qkvbuf, 768, 768, 2304, 768);
        attn_score<<<dim3(4, 4, BATCH * NHEAD), 256, 0, stream>>>(qkvbuf, S);
        const int um = (d >= 9);
        float* mk = masks + (size_t)(um ? d - 9 : 0) * BATCH * NTOK;
        if (um) mask_kernel<<<BATCH, 256, 0, stream>>>(S, mk);
        softmax_kernel<<<dim3(50, BATCH * NHEAD), 256, 0, stream>>>(S, mk, um);
        attn_pv<<<dim3(4, BATCH * NHEAD), 256, 0, stream>>>(S, qkvbuf, a_buf);
        gemm_bt<EPI_RES><<<dim3(6, 99), 256, 0, stream>>>(a_buf, proj_w + (size_t)d * CDIM * CDIM,
                                                          proj_b + d * CDIM, t_buf, 768, 768, 768, 768);
        ln_kernel<<<12672, 256, 0, stream>>>(t_buf, ln2_w + d * CDIM, ln2_b + d * CDIM, a_buf);
        gemm_bt<EPI_GELU><<<dim3(24, 99), 256, 0, stream>>>(a_buf, fc1_w + (size_t)d * 4 * CDIM * CDIM,
                                                            fc1_b + d * 4 * CDIM, h_buf, 768, 768, 3072, 768);
        gemm_bt<EPI_RES><<<dim3(6, 99), 256, 0, stream>>>(h_buf, fc2_w + (size_t)d * 4 * CDIM * CDIM,
                                                          fc2_b + d * CDIM, t_buf, 3072, 3072, 768, 3072);
    }
    ln_kernel<<<12672, 256, 0, stream>>>(t_buf, norm_w, norm_b, a_buf);
    ssum_kernel<<<BATCH, 256, 0, stream>>>(a_buf, ssum);
    logits_kernel<<<200, 256, 0, stream>>>(ssum, head_w, head_b, out);
    mask_out_kernel<<<BATCH, 256, 0, stream>>>(masks, gk, out);
}

// Round 3
// 6350.599 us; speedup vs baseline: 1.6228x; 1.6228x over previous
//
#include <hip/hip_runtime.h>

#define BATCH 64
#define NTOK 198
#define CDIM 768
#define NHEAD 12
#define NLAYER 12
#define ATT_SCALE 0.125f
#define SLD 256      // score row stride (bf16)
#define LDSK 40      // padded LDS stride for attention tiles (bf16)

typedef __attribute__((ext_vector_type(8))) __bf16 bf16x8;
typedef __attribute__((ext_vector_type(4))) float f32x4;
typedef const void __attribute__((address_space(1))) GV;
typedef void __attribute__((address_space(3))) LV;

__device__ __forceinline__ unsigned f2bf_bits(float a) {
    unsigned u = __builtin_bit_cast(unsigned, a);
    return (u + 0x7FFFu + ((u >> 16) & 1u)) >> 16;   // RNE; finite inputs
}
__device__ __forceinline__ unsigned short f2bf(float a) { return (unsigned short)f2bf_bits(a); }
__device__ __forceinline__ float bf2f(unsigned short u) {
    return __builtin_bit_cast(float, ((unsigned)u) << 16);
}

#define EPI_NONE 0
#define EPI_BIAS 1
#define EPI_GELU 2
#define EPI_RES  3

__global__ __launch_bounds__(256)
void cvt_kernel(const float* __restrict__ src, unsigned short* __restrict__ dst, int n4)
{
    int i = blockIdx.x * 256 + threadIdx.x;
    if (i < n4) {
        float4 v = ((const float4*)src)[i];
        ushort4 o;
        o.x = f2bf(v.x); o.y = f2bf(v.y); o.z = f2bf(v.z); o.w = f2bf(v.w);
        ((ushort4*)dst)[i] = o;
    }
}

// C[M,N] = A[M,K](bf16) * Bt[N,K](bf16)^T ; dims multiples of 128 / K of 32. No guards.
template<int EPI, bool BOUT>
__global__ __launch_bounds__(256)
void gemm_bf(const unsigned short* __restrict__ A, const unsigned short* __restrict__ Bt,
             const float* __restrict__ bias, float* __restrict__ Cf,
             unsigned short* __restrict__ Cb, int lda, int ldb, int ldc, int K)
{
    __shared__ unsigned short sA[128 * 32];
    __shared__ unsigned short sB[128 * 32];
    const int tid = threadIdx.x;
    const int lane = tid & 63, wave = tid >> 6;
    const int wm = wave >> 1, wn = wave & 1;
    const int quad = lane >> 4, r = lane & 15;
    const int m0 = blockIdx.y * 128, n0 = blockIdx.x * 128;

    const int srow = tid >> 2, sch = (tid & 3) << 3;   // 16B per lane, lane-linear
    const unsigned short* aG0 = A + (size_t)(m0 + srow) * lda + sch;
    const unsigned short* aG1 = A + (size_t)(m0 + 64 + srow) * lda + sch;
    const unsigned short* bG0 = Bt + (size_t)(n0 + srow) * ldb + sch;
    const unsigned short* bG1 = Bt + (size_t)(n0 + 64 + srow) * ldb + sch;
    unsigned short* lA0 = sA + srow * 32 + sch;
    unsigned short* lA1 = sA + (64 + srow) * 32 + sch;
    unsigned short* lB0 = sB + srow * 32 + sch;
    unsigned short* lB1 = sB + (64 + srow) * 32 + sch;

    const f32x4 vzero = {0.f, 0.f, 0.f, 0.f};
    f32x4 acc[4][4];
#pragma unroll
    for (int i = 0; i < 4; ++i)
#pragma unroll
        for (int j = 0; j < 4; ++j) acc[i][j] = vzero;

    for (int k0 = 0; k0 < K; k0 += 32) {
        __builtin_amdgcn_global_load_lds((GV*)(aG0 + k0), (LV*)lA0, 16, 0, 0);
        __builtin_amdgcn_global_load_lds((GV*)(aG1 + k0), (LV*)lA1, 16, 0, 0);
        __builtin_amdgcn_global_load_lds((GV*)(bG0 + k0), (LV*)lB0, 16, 0, 0);
        __builtin_amdgcn_global_load_lds((GV*)(bG1 + k0), (LV*)lB1, 16, 0, 0);
        __syncthreads();
        bf16x8 af[4], bfv[4];
#pragma unroll
        for (int i = 0; i < 4; ++i)
            af[i] = *(const bf16x8*)(sA + (wm*64 + i*16 + r) * 32 + quad*8);
#pragma unroll
        for (int j = 0; j < 4; ++j)
            bfv[j] = *(const bf16x8*)(sB + (wn*64 + j*16 + r) * 32 + quad*8);
#pragma unroll
        for (int i = 0; i < 4; ++i)
#pragma unroll
            for (int j = 0; j < 4; ++j)
                acc[i][j] = __builtin_amdgcn_mfma_f32_16x16x32_bf16(af[i], bfv[j], acc[i][j], 0, 0, 0);
        __syncthreads();
    }

#pragma unroll
    for (int i = 0; i < 4; ++i) {
        const int row0 = m0 + wm*64 + i*16 + quad*4;
#pragma unroll
        for (int j = 0; j < 4; ++j) {
            const int col = n0 + wn*64 + j*16 + r;
            float bv = 0.f;
            if (EPI != EPI_NONE) bv = bias[col];
#pragma unroll
            for (int t = 0; t < 4; ++t) {
                size_t idx = (size_t)(row0 + t) * ldc + col;
                float v = acc[i][j][t];
                if (EPI == EPI_GELU) {
                    float u = v + bv;
                    v = 0.5f * u * (1.f + erff(u * 0.70710678f));
                } else if (EPI == EPI_BIAS) {
                    v = v + bv;
                } else if (EPI == EPI_RES) {
                    v = Cf[idx] + v + bv;
                }
                if (BOUT) Cb[idx] = f2bf(v);
                else      Cf[idx] = v;
            }
        }
    }
}

__global__ __launch_bounds__(256)
void im2col_kernel(const float* __restrict__ x, unsigned short* __restrict__ out)
{
    int idx = blockIdx.x * 256 + threadIdx.x;       // 12544*768 total, exact
    int kk = idx % 768;
    int m = idx / 768;
    int c = kk >> 8, rr = kk & 255, i = rr >> 4, j = rr & 15;
    int b = m / 196, p = m % 196, ph = p / 14, pw = p % 14;
    out[idx] = f2bf(x[(((size_t)(b*3 + c) * 224) + ph*16 + i) * 224 + pw*16 + j]);
}

__global__ __launch_bounds__(256)
void build_t_kernel(const float* __restrict__ pbuf, const float* __restrict__ cls_tok,
                    const float* __restrict__ loc_tok, const float* __restrict__ pos_emb,
                    const float* __restrict__ loc_emb, float* __restrict__ t)
{
    int idx = blockIdx.x * 256 + threadIdx.x;       // 64*198*768, exact
    int c = idx % CDIM;
    int bn = idx / CDIM;
    int n = bn % NTOK, b = bn / NTOK;
    float v;
    if (n == 0)          v = cls_tok[c] + pos_emb[c];
    else if (n == NTOK-1) v = loc_tok[c] + loc_emb[c];
    else                 v = pbuf[((size_t)(b*196 + n - 1)) * CDIM + c] + pos_emb[(size_t)n * CDIM + c];
    t[idx] = v;
}

template<bool BOUT>
__global__ __launch_bounds__(256)
void ln_kernel(const float* __restrict__ x, const float* __restrict__ w,
               const float* __restrict__ bb, float* __restrict__ yf,
               unsigned short* __restrict__ yb)
{
    int row = blockIdx.x;
    const float* xr = x + (size_t)row * CDIM;
    int tid = threadIdx.x;
    float v0 = xr[tid], v1 = xr[tid + 256], v2 = xr[tid + 512];
    float s = v0 + v1 + v2;
    float q = v0*v0 + v1*v1 + v2*v2;
#pragma unroll
    for (int off = 32; off; off >>= 1) {
        s += __shfl_down(s, off, 64);
        q += __shfl_down(q, off, 64);
    }
    __shared__ float rs[4], rq[4];
    int lane = tid & 63, wv = tid >> 6;
    if (lane == 0) { rs[wv] = s; rq[wv] = q; }
    __syncthreads();
    float S = rs[0] + rs[1] + rs[2] + rs[3];
    float Q = rq[0] + rq[1] + rq[2] + rq[3];
    float mean = S * (1.f / 768.f);
    float var = Q * (1.f / 768.f) - mean * mean;
    float rstd = rsqrtf(var + 1e-5f);
    float o0 = (v0 - mean) * rstd * w[tid]       + bb[tid];
    float o1 = (v1 - mean) * rstd * w[tid + 256] + bb[tid + 256];
    float o2 = (v2 - mean) * rstd * w[tid + 512] + bb[tid + 512];
    if (BOUT) {
        unsigned short* yr = yb + (size_t)row * CDIM;
        yr[tid] = f2bf(o0); yr[tid + 256] = f2bf(o1); yr[tid + 512] = f2bf(o2);
    } else {
        float* yr = yf + (size_t)row * CDIM;
        yr[tid] = o0; yr[tid + 256] = o1; yr[tid + 512] = o2;
    }
}

// S[bh, q, k] = scale * Q.K^T   (tiles 64x64, K=64); bf16 in, bf16 out
__global__ __launch_bounds__(256)
void attn_score(const unsigned short* __restrict__ qkv, unsigned short* __restrict__ S)
{
    const int bh = blockIdx.z, b = bh / NHEAD, h = bh % NHEAD;
    const int m0 = blockIdx.y * 64, n0 = blockIdx.x * 64;
    __shared__ unsigned short sQ[64 * 72];
    __shared__ unsigned short sK[64 * 72];
    const int tid = threadIdx.x;
    const int lane = tid & 63, wave = tid >> 6;
    const int wm = wave >> 1, wn = wave & 1;
    const int quad = lane >> 4, r = lane & 15;

    const unsigned short* base = qkv + (size_t)b * NTOK * 2304 + h * 64;
    {
        const int srow = tid >> 2, seg = (tid & 3) << 4;   // 16 bf16 = 32 B each
        int gq = m0 + srow, gk = n0 + srow;
        uint4 z = {0u, 0u, 0u, 0u};
        uint4 q0 = z, q1 = z, k0v = z, k1v = z;
        if (gq < NTOK) {
            const uint4* p = (const uint4*)(base + (size_t)gq * 2304 + seg);
            q0 = p[0]; q1 = p[1];
        }
        if (gk < NTOK) {
            const uint4* p = (const uint4*)(base + (size_t)gk * 2304 + 768 + seg);
            k0v = p[0]; k1v = p[1];
        }
        uint4* wq = (uint4*)(sQ + srow * 72 + seg); wq[0] = q0; wq[1] = q1;
        uint4* wk = (uint4*)(sK + srow * 72 + seg); wk[0] = k0v; wk[1] = k1v;
    }
    __syncthreads();

    const f32x4 vzero = {0.f, 0.f, 0.f, 0.f};
    f32x4 acc[2][2] = {{vzero, vzero}, {vzero, vzero}};
#pragma unroll
    for (int ks = 0; ks < 2; ++ks) {
        bf16x8 aq0 = *(const bf16x8*)(sQ + (wm*32 + r)      * 72 + ks*32 + quad*8);
        bf16x8 aq1 = *(const bf16x8*)(sQ + (wm*32 + 16 + r) * 72 + ks*32 + quad*8);
        bf16x8 bk0 = *(const bf16x8*)(sK + (wn*32 + r)      * 72 + ks*32 + quad*8);
        bf16x8 bk1 = *(const bf16x8*)(sK + (wn*32 + 16 + r) * 72 + ks*32 + quad*8);
        acc[0][0] = __builtin_amdgcn_mfma_f32_16x16x32_bf16(aq0, bk0, acc[0][0], 0, 0, 0);
        acc[0][1] = __builtin_amdgcn_mfma_f32_16x16x32_bf16(aq0, bk1, acc[0][1], 0, 0, 0);
        acc[1][0] = __builtin_amdgcn_mfma_f32_16x16x32_bf16(aq1, bk0, acc[1][0], 0, 0, 0);
        acc[1][1] = __builtin_amdgcn_mfma_f32_16x16x32_bf16(aq1, bk1, acc[1][1], 0, 0, 0);
    }
#pragma unroll
    for (int i = 0; i < 2; ++i)
#pragma unroll
        for (int j = 0; j < 2; ++j)
#pragma unroll
            for (int t = 0; t < 4; ++t) {
                int qr = m0 + wm*32 + i*16 + quad*4 + t;
                int kc = n0 + wn*32 + j*16 + r;
                if (qr < NTOK)   // kc < SLD always; cols >=198 are exact zeros
                    S[((size_t)bh * NTOK + qr) * SLD + kc] = f2bf(acc[i][j][t] * ATT_SCALE);
            }
}

__global__ __launch_bounds__(256)
void mask_kernel(const unsigned short* __restrict__ S, float* __restrict__ mk)
{
    int b = blockIdx.x, kc = threadIdx.x;
    if (kc >= NTOK) return;
    float s = 0.f;
#pragma unroll
    for (int h = 0; h < NHEAD; ++h)
        s += bf2f(S[((size_t)(b * NHEAD + h) * NTOK + (NTOK - 1)) * SLD + kc]);
    s *= (1.f / NHEAD);
    mk[b * NTOK + kc] = 1.f / (1.f + __expf(-s));
}

__global__ __launch_bounds__(256)
void softmax_kernel(unsigned short* __restrict__ S, const float* __restrict__ mk, int use_mask)
{
    int bh = blockIdx.y, b = bh / NHEAD;
    int qr = blockIdx.x * 4 + (threadIdx.x >> 6);
    int lane = threadIdx.x & 63;
    if (qr >= NTOK) return;
    unsigned short* row = S + ((size_t)bh * NTOK + qr) * SLD;
    float v0 = bf2f(row[lane]);
    float v1 = bf2f(row[lane + 64]);
    float v2 = bf2f(row[lane + 128]);
    float v3 = (lane + 192 < NTOK) ? bf2f(row[lane + 192]) : -1e30f;
    float mx = fmaxf(fmaxf(v0, v1), fmaxf(v2, v3));
#pragma unroll
    for (int off = 32; off; off >>= 1) mx = fmaxf(mx, __shfl_xor(mx, off, 64));
    v0 = __expf(v0 - mx); v1 = __expf(v1 - mx); v2 = __expf(v2 - mx);
    v3 = (lane + 192 < NTOK) ? __expf(v3 - mx) : 0.f;
    float sm = v0 + v1 + v2 + v3;
#pragma unroll
    for (int off = 32; off; off >>= 1) sm += __shfl_xor(sm, off, 64);
    float inv = 1.f / sm;
    v0 *= inv; v1 *= inv; v2 *= inv; v3 *= inv;
    if (use_mask) {
        v0 *= mk[b * NTOK + lane];
        v1 *= mk[b * NTOK + lane + 64];
        v2 *= mk[b * NTOK + lane + 128];
        if (lane + 192 < NTOK) v3 *= mk[b * NTOK + lane + 192];
    }
    row[lane] = f2bf(v0); row[lane + 64] = f2bf(v1); row[lane + 128] = f2bf(v2);
    if (lane + 192 < NTOK) row[lane + 192] = f2bf(v3);
}

// O = P.V  (tiles 64 q-rows x 64 hd, K over 198); bf16 in, bf16 out
__global__ __launch_bounds__(256)
void attn_pv(const unsigned short* __restrict__ S, const unsigned short* __restrict__ qkv,
             unsigned short* __restrict__ o)
{
    const int bh = blockIdx.y, b = bh / NHEAD, h = bh % NHEAD;
    const int m0 = blockIdx.x * 64;
    __shared__ unsigned short sP[64 * LDSK];
    __shared__ unsigned short sVt[64 * LDSK];
    const int tid = threadIdx.x;
    const int lane = tid & 63, wave = tid >> 6;
    const int wm = wave >> 1, wn = wave & 1;
    const int quad = lane >> 4, r = lane & 15;
    const unsigned short* Pb = S + (size_t)bh * NTOK * SLD;
    const unsigned short* vb = qkv + (size_t)b * NTOK * 2304 + 1536 + h * 64;

    const f32x4 vzero = {0.f, 0.f, 0.f, 0.f};
    f32x4 acc[2][2] = {{vzero, vzero}, {vzero, vzero}};

    const int prow = tid >> 2, pch = (tid & 3) << 3;   // P: 64 rows x 4 chunks of 8
    const int vk = tid & 31, vh = (tid >> 5) << 3;     // V: transpose

    for (int k0 = 0; k0 < NTOK; k0 += 32) {
        __syncthreads();
        {
            int gq = m0 + prow;
            uint4 pv = {0u, 0u, 0u, 0u};
            if (gq < NTOK) pv = *(const uint4*)(Pb + (size_t)gq * SLD + k0 + pch);
            *(uint4*)(sP + prow * LDSK + pch) = pv;
        }
        {
            int gk = k0 + vk;
            if (gk < NTOK) {
                const unsigned short* p = vb + (size_t)gk * 2304 + vh;
                uint4 vv = *(const uint4*)p;
                const unsigned short* e = (const unsigned short*)&vv;
#pragma unroll
                for (int q2 = 0; q2 < 8; ++q2) sVt[(vh + q2) * LDSK + vk] = e[q2];
            } else {
#pragma unroll
                for (int q2 = 0; q2 < 8; ++q2) sVt[(vh + q2) * LDSK + vk] = 0;
            }
        }
        __syncthreads();
        bf16x8 ap0 = *(const bf16x8*)(sP + (wm*32 + r)       * LDSK + quad*8);
        bf16x8 ap1 = *(const bf16x8*)(sP + (wm*32 + 16 + r)  * LDSK + quad*8);
        bf16x8 bv0 = *(const bf16x8*)(sVt + (wn*32 + r)      * LDSK + quad*8);
        bf16x8 bv1 = *(const bf16x8*)(sVt + (wn*32 + 16 + r) * LDSK + quad*8);
        acc[0][0] = __builtin_amdgcn_mfma_f32_16x16x32_bf16(ap0, bv0, acc[0][0], 0, 0, 0);
        acc[0][1] = __builtin_amdgcn_mfma_f32_16x16x32_bf16(ap0, bv1, acc[0][1], 0, 0, 0);
        acc[1][0] = __builtin_amdgcn_mfma_f32_16x16x32_bf16(ap1, bv0, acc[1][0], 0, 0, 0);
        acc[1][1] = __builtin_amdgcn_mfma_f32_16x16x32_bf16(ap1, bv1, acc[1][1], 0, 0, 0);
    }
#pragma unroll
    for (int i = 0; i < 2; ++i) {
        int qr0 = m0 + wm*32 + i*16 + quad*4;
#pragma unroll
        for (int j = 0; j < 2; ++j) {
            int hd = wn*32 + j*16 + r;
#pragma unroll
            for (int t = 0; t < 4; ++t) {
                int qr = qr0 + t;
                if (qr < NTOK)
                    o[((size_t)b * NTOK + qr) * CDIM + h * 64 + hd] = f2bf(acc[i][j][t]);
            }
        }
    }
}

// 9 shifted-window sums of the final-LN patch tokens: Ssum[b, c*9 + di*3 + dj]
__global__ __launch_bounds__(256)
void ssum_kernel(const float* __restrict__ tn, float* __restrict__ ss)
{
    int b = blockIdx.x;
    for (int c = threadIdx.x; c < CDIM; c += 256) {
        float rs0[14], rs1[14], rs2[14];
#pragma unroll
        for (int y = 0; y < 14; ++y) {
            float sum = 0.f, first = 0.f, last = 0.f;
#pragma unroll
            for (int xx = 0; xx < 14; ++xx) {
                float v = tn[((size_t)(b * NTOK + 1 + y * 14 + xx)) * CDIM + c];
                sum += v;
                if (xx == 0) first = v;
                if (xx == 13) last = v;
            }
            rs1[y] = sum; rs0[y] = sum - last; rs2[y] = sum - first;
        }
        float a0 = 0.f, a1 = 0.f, a2 = 0.f;
#pragma unroll
        for (int y = 0; y < 14; ++y) { a0 += rs0[y]; a1 += rs1[y]; a2 += rs2[y]; }
        float* outp = ss + (size_t)b * 6912 + c * 9;
        outp[0] = a0 - rs0[13]; outp[1] = a1 - rs1[13]; outp[2] = a2 - rs2[13];
        outp[3] = a0;           outp[4] = a1;           outp[5] = a2;
        outp[6] = a0 - rs0[0];  outp[7] = a1 - rs1[0];  outp[8] = a2 - rs2[0];
    }
}

__global__ __launch_bounds__(256)
void logits_kernel(const float* __restrict__ ssum, const float* __restrict__ hw,
                   const float* __restrict__ hb, float* __restrict__ out)
{
    int cls = blockIdx.x;                       // 200
    int b = blockIdx.y * 4 + (threadIdx.x >> 6); // 16 * 4 waves
    int lane = threadIdx.x & 63;
    const float* wr = hw + (size_t)cls * 6912;
    const float* sr = ssum + (size_t)b * 6912;
    float s = 0.f;
    for (int k = lane * 4; k < 6912; k += 256) {
        float4 a = *(const float4*)(sr + k);
        float4 w4 = *(const float4*)(wr + k);
        s += a.x * w4.x + a.y * w4.y + a.z * w4.z + a.w * w4.w;
    }
#pragma unroll
    for (int off = 32; off; off >>= 1) s += __shfl_down(s, off, 64);
    if (lane == 0) out[b * 200 + cls] = hb[cls] + s * (1.f / 196.f);
}

__global__ __launch_bounds__(256)
void mask_out_kernel(const float* __restrict__ masks, const float* __restrict__ gk,
                     float* __restrict__ out)
{
    int b = blockIdx.x, tid = threadIdx.x;
    __shared__ float sm[196];
    float ma = 0.f;
    if (tid < 196) {
        float m0 = masks[((size_t)(0 * BATCH + b)) * NTOK + tid + 1];
        float m1 = masks[((size_t)(1 * BATCH + b)) * NTOK + tid + 1];
        float m2 = masks[((size_t)(2 * BATCH + b)) * NTOK + tid + 1];
        ma = (m0 + m1 + m2) * (1.f / 3.f);
        sm[tid] = ma;
    }
    __syncthreads();
    float mavg = 0.f;
    if (tid < 196) {
        int i = tid / 14, j = tid % 14;
#pragma unroll
        for (int di = 0; di < 3; ++di)
#pragma unroll
            for (int dj = 0; dj < 3; ++dj) {
                int y = i + di - 1, xx = j + dj - 1;
                if (y >= 0 && y < 14 && xx >= 0 && xx < 14)
                    mavg += gk[di * 3 + dj] * sm[y * 14 + xx];
            }
    }
    float rg = (1.f - mavg) * mavg;
    if (tid >= 196) { ma = 0.f; rg = 0.f; }
    float s1 = ma, s2 = rg;
#pragma unroll
    for (int off = 32; off; off >>= 1) { s1 += __shfl_down(s1, off, 64); s2 += __shfl_down(s2, off, 64); }
    __shared__ float r1[4], r2[4];
    if ((tid & 63) == 0) { r1[tid >> 6] = s1; r2[tid >> 6] = s2; }
    __syncthreads();
    if (tid == 0) {
        out[12800 + b] = (r1[0] + r1[1] + r1[2] + r1[3]) * (1.f / 196.f);
        out[12864 + b] = (r2[0] + r2[1] + r2[2] + r2[3]) * (1.f / 196.f);
    }
}

extern "C" void kernel_launch(void* const* d_in, const int* in_sizes, int n_in,
                              void* d_out, int out_size, void* d_ws, size_t ws_size,
                              hipStream_t stream)
{
    const float* x       = (const float*)d_in[0];
    const float* patch_w = (const float*)d_in[1];
    const float* patch_b = (const float*)d_in[2];
    const float* cls_tok = (const float*)d_in[3];
    const float* loc_tok = (const float*)d_in[4];
    const float* pos_emb = (const float*)d_in[5];
    const float* loc_emb = (const float*)d_in[6];
    const float* ln1_w   = (const float*)d_in[7];
    const float* ln1_b   = (const float*)d_in[8];
    const float* qkv_w   = (const float*)d_in[9];
    const float* proj_w  = (const float*)d_in[10];
    const float* proj_b  = (const float*)d_in[11];
    const float* ln2_w   = (const float*)d_in[12];
    const float* ln2_b   = (const float*)d_in[13];
    const float* fc1_w   = (const float*)d_in[14];
    const float* fc1_b   = (const float*)d_in[15];
    const float* fc2_w   = (const float*)d_in[16];
    const float* fc2_b   = (const float*)d_in[17];
    const float* norm_w  = (const float*)d_in[18];
    const float* norm_b  = (const float*)d_in[19];
    const float* head_w  = (const float*)d_in[20];
    const float* head_b  = (const float*)d_in[21];
    const float* gk      = (const float*)d_in[22];
    float* out = (float*)d_out;
    float* ws = (float*)d_ws;

    // workspace layout (float-offsets); total 91,903,104 floats = 367.6 MB
    unsigned short* wqkv   = (unsigned short*)ws;          // 21,233,664 bf16
    unsigned short* wproj  = wqkv + 21233664;              //  7,077,888
    unsigned short* wfc1   = wproj + 7077888;              // 28,311,552
    unsigned short* wfc2   = wfc1 + 28311552;              // 28,311,552
    unsigned short* wpatch = wfc2 + 28311552;              //    589,824
    float* t_buf = ws + 42762240;                          // 9,732,096 f32
    unsigned short* a_bf  = (unsigned short*)(ws + 52494336);  // 9,732,096 bf16
    unsigned short* qkvbf = (unsigned short*)(ws + 57360384);  // 29,196,288 bf16
    float* Sreg   = ws + 71958528;                         // 19,464,192 f32-equiv region
    float* ssum   = ws + 91422720;                         // 442,368
    float* masks  = ws + 91865088;                         // 38,016
    unsigned short* Sb = (unsigned short*)Sreg;            // scores 768*198*256 bf16 (fits exactly)
    unsigned short* h_bf = (unsigned short*)Sreg;          // fc1 out (same region, disjoint lifetime)
    unsigned short* im2c = (unsigned short*)Sreg;          // im2col (pre-loop)
    float* p_buf = (float*)qkvbf;                          // patch GEMM out (pre-loop)
    float* fin   = (float*)qkvbf;                          // final LN out (post-loop)

    cvt_kernel<<<20736, 256, 0, stream>>>(qkv_w,  wqkv,  5308416);
    cvt_kernel<<< 6912, 256, 0, stream>>>(proj_w, wproj, 1769472);
    cvt_kernel<<<27648, 256, 0, stream>>>(fc1_w,  wfc1,  7077888);
    cvt_kernel<<<27648, 256, 0, stream>>>(fc2_w,  wfc2,  7077888);
    cvt_kernel<<<  576, 256, 0, stream>>>(patch_w, wpatch, 147456);

    im2col_kernel<<<37632, 256, 0, stream>>>(x, im2c);
    gemm_bf<EPI_BIAS, false><<<dim3(6, 98), 256, 0, stream>>>(im2c, wpatch, patch_b, p_buf, nullptr, 768, 768, 768, 768);
    build_t_kernel<<<38016, 256, 0, stream>>>(p_buf, cls_tok, loc_tok, pos_emb, loc_emb, t_buf);

    for (int d = 0; d < NLAYER; ++d) {
        ln_kernel<true><<<12672, 256, 0, stream>>>(t_buf, ln1_w + d * CDIM, ln1_b + d * CDIM, nullptr, a_bf);
        gemm_bf<EPI_NONE, true><<<dim3(18, 99), 256, 0, stream>>>(a_bf, wqkv + (size_t)d * 1769472,
                                                                  nullptr, nullptr, qkvbf, 768, 768, 2304, 768);
        attn_score<<<dim3(4, 4, BATCH * NHEAD), 256, 0, stream>>>(qkvbf, Sb);
        const int um = (d >= 9);
        float* mk = masks + (size_t)(um ? d - 9 : 0) * BATCH * NTOK;
        if (um) mask_kernel<<<BATCH, 256, 0, stream>>>(Sb, mk);
        softmax_kernel<<<dim3(50, BATCH * NHEAD), 256, 0, stream>>>(Sb, mk, um);
        attn_pv<<<dim3(4, BATCH * NHEAD), 256, 0, stream>>>(Sb, qkvbf, a_bf);
        gemm_bf<EPI_RES, false><<<dim3(6, 99), 256, 0, stream>>>(a_bf, wproj + (size_t)d * 589824,
                                                                 proj_b + d * CDIM, t_buf, nullptr, 768, 768, 768, 768);
        ln_kernel<true><<<12672, 256, 0, stream>>>(t_buf, ln2_w + d * CDIM, ln2_b + d * CDIM, nullptr, a_bf);
        gemm_bf<EPI_GELU, true><<<dim3(24, 99), 256, 0, stream>>>(a_bf, wfc1 + (size_t)d * 2359296,
                                                                  fc1_b + d * 3072, nullptr, h_bf, 768, 768, 3072, 768);
        gemm_bf<EPI_RES, false><<<dim3(6, 99), 256, 0, stream>>>(h_bf, wfc2 + (size_t)d * 2359296,
                                                                 fc2_b + d * CDIM, t_buf, nullptr, 3072, 3072, 768, 3072);
    }
    ln_kernel<false><<<12672, 256, 0, stream>>>(t_buf, norm_w, norm_b, fin, nullptr);
    ssum_kernel<<<BATCH, 256, 0, stream>>>(fin, ssum);
    logits_kernel<<<dim3(200, 16), 256, 0, stream>>>(ssum, head_w, head_b, out);
    mask_out_kernel<<<BATCH, 256, 0, stream>>>(masks, gk, out);
}